// Round 2
// baseline (222.956 us; speedup 1.0000x reference)
//
#include <hip/hip_runtime.h>

#define NROWS 8192
#define INCH 10
#define NQKV 33
#define OUTCH 11
#define KB 256           // K/V tile rows staged in LDS per iteration
#define SPLIT 2          // k-dimension split across blocks
#define KCHUNK (NROWS / SPLIT)

// ws layout (float4 units):
//   [0      , 3*NROWS)  : q planes  (scaled by IN_CH^-0.5 * log2(e))
//   [3*NROWS, 6*NROWS)  : k planes
//   [6*NROWS, 9*NROWS)  : v planes
//   [9*NROWS, 9*NROWS + SPLIT*3*NROWS) : partials
//       partial[kc][c][row], c=0: o0..3, c=1: o4..7, c=2: {o8,o9,o10,l}
#define PART_BASE (9 * NROWS)

// ---------------------------------------------------------------------------
// Kernel A: LayerNorm + Linear(10 -> 33) -> q*scale*log2e, k, v as float4
// planes ws[(part*3 + c)*NROWS + row]. Pad elements 0.
// ---------------------------------------------------------------------------
__global__ __launch_bounds__(256) void qkv_ln_kernel(
    const float* __restrict__ x, const float* __restrict__ gamma,
    const float* __restrict__ beta, const float* __restrict__ W,
    float4* __restrict__ ws) {
  __shared__ float sW[NQKV * INCH];
  __shared__ float sg[INCH];
  __shared__ float sb[INCH];
  int tid = threadIdx.x;
  for (int i = tid; i < NQKV * INCH; i += 256) sW[i] = W[i];
  if (tid < INCH) { sg[tid] = gamma[tid]; sb[tid] = beta[tid]; }
  __syncthreads();

  int row = blockIdx.x * 256 + tid;
  float xv[INCH];
#pragma unroll
  for (int i = 0; i < INCH; ++i) xv[i] = x[row * INCH + i];

  float mu = 0.f;
#pragma unroll
  for (int i = 0; i < INCH; ++i) mu += xv[i];
  mu *= (1.0f / INCH);
  float var = 0.f;
#pragma unroll
  for (int i = 0; i < INCH; ++i) { float d = xv[i] - mu; var += d * d; }
  var *= (1.0f / INCH);
  float rstd = rsqrtf(var + 1e-5f);
  float h[INCH];
#pragma unroll
  for (int i = 0; i < INCH; ++i) h[i] = (xv[i] - mu) * rstd * sg[i] + sb[i];

  float acc[NQKV];
#pragma unroll
  for (int oc = 0; oc < NQKV; ++oc) {
    float s = 0.f;
#pragma unroll
    for (int i = 0; i < INCH; ++i) s += h[i] * sW[oc * INCH + i];
    acc[oc] = s;
  }
  // Fold softmax exp->exp2 conversion into q: exp(s) = exp2(s*log2e).
  const float qscale = 0.31622776601683794f * 1.4426950408889634f;
#pragma unroll
  for (int oc = 0; oc < OUTCH; ++oc) acc[oc] *= qscale;

#pragma unroll
  for (int p = 0; p < 3; ++p) {
#pragma unroll
    for (int c = 0; c < 3; ++c) {
      float4 v;
      const int d0 = 4 * c;
      v.x = (d0 + 0 < OUTCH) ? acc[p * OUTCH + d0 + 0] : 0.f;
      v.y = (d0 + 1 < OUTCH) ? acc[p * OUTCH + d0 + 1] : 0.f;
      v.z = (d0 + 2 < OUTCH) ? acc[p * OUTCH + d0 + 2] : 0.f;
      v.w = (d0 + 3 < OUTCH) ? acc[p * OUTCH + d0 + 3] : 0.f;
      ws[(p * 3 + c) * NROWS + row] = v;
    }
  }
}

// ---------------------------------------------------------------------------
// Kernel B: streaming (un-maxed) softmax partial. No row-max needed: |s| is
// bounded ~14, exp2 args bounded ~20 -> fp32-safe; softmax is shift-invariant.
// Grid = 512 q-blocks x SPLIT k-chunks. Block = 256 thr = 4 waves; wave owns
// 4 q-rows in VGPRs; lane = k-slot. KB-row K/V tiles staged in LDS.
// Each block writes un-normalized (sum p*v, sum p) for its k-chunk.
// ---------------------------------------------------------------------------
__global__ __launch_bounds__(256, 4) void attn_kernel(
    const float4* __restrict__ ws, float4* __restrict__ part) {
  __shared__ float4 sK[3 * KB];  // 12 KB
  __shared__ float4 sV[3 * KB];  // 12 KB
  int tid = threadIdx.x;
  int lane = tid & 63;
  int wv = tid >> 6;
  int qc = blockIdx.x >> 1;
  int kc = blockIdx.x & 1;
  int row0 = qc * 16 + wv * 4;

  const float4* Q = ws;
  const float4* K = ws + 3 * NROWS;
  const float4* V = ws + 6 * NROWS;

  float q[4][12];
#pragma unroll
  for (int u = 0; u < 4; ++u) {
#pragma unroll
    for (int c = 0; c < 3; ++c) {
      float4 t = Q[c * NROWS + row0 + u];
      q[u][4 * c + 0] = t.x;
      q[u][4 * c + 1] = t.y;
      q[u][4 * c + 2] = t.z;
      q[u][4 * c + 3] = t.w;
    }
  }

  float l[4] = {0.f, 0.f, 0.f, 0.f};
  float o[4][OUTCH];
#pragma unroll
  for (int u = 0; u < 4; ++u)
#pragma unroll
    for (int d = 0; d < OUTCH; ++d) o[u][d] = 0.f;

  const int jbase = kc * KCHUNK;
  for (int tile = 0; tile < KCHUNK / KB; ++tile) {
    const int jb = jbase + tile * KB;
    __syncthreads();
#pragma unroll
    for (int i = 0; i < (3 * KB) / 256; ++i) {
      int f = tid + 256 * i;      // [0, 3*KB)
      int c = f >> 8;             // KB == 256
      int j = f & (KB - 1);
      sK[f] = K[c * NROWS + jb + j];
      sV[f] = V[c * NROWS + jb + j];
    }
    __syncthreads();

#pragma unroll
    for (int it = 0; it < KB / 64; ++it) {
      int j = it * 64 + lane;
      float4 ka = sK[j], kb = sK[KB + j], kc4 = sK[2 * KB + j];
      float4 va = sV[j], vb = sV[KB + j], vc4 = sV[2 * KB + j];
      float kk[12] = {ka.x, ka.y, ka.z, ka.w, kb.x, kb.y,
                      kb.z, kb.w, kc4.x, kc4.y, kc4.z, kc4.w};
      float vv[12] = {va.x, va.y, va.z, va.w, vb.x, vb.y,
                      vb.z, vb.w, vc4.x, vc4.y, vc4.z, vc4.w};
#pragma unroll
      for (int u = 0; u < 4; ++u) {
        float s = q[u][0] * kk[0];
#pragma unroll
        for (int d = 1; d < OUTCH; ++d) s += q[u][d] * kk[d];
        float p = exp2f(s);  // q pre-scaled by log2e -> raw v_exp_f32
        l[u] += p;
#pragma unroll
        for (int d = 0; d < OUTCH; ++d) o[u][d] += p * vv[d];
      }
    }
  }

  // Butterfly sum of (o, l) packed as 12 floats across the 64 lanes.
#pragma unroll
  for (int u = 0; u < 4; ++u) {
    float r[12];
#pragma unroll
    for (int d = 0; d < OUTCH; ++d) r[d] = o[u][d];
    r[11] = l[u];
#pragma unroll
    for (int m = 1; m < 64; m <<= 1) {
#pragma unroll
      for (int d = 0; d < 12; ++d) r[d] += __shfl_xor(r[d], m, 64);
    }
    if (lane == 0) {
      int row = row0 + u;
      part[(kc * 3 + 0) * NROWS + row] = make_float4(r[0], r[1], r[2], r[3]);
      part[(kc * 3 + 1) * NROWS + row] = make_float4(r[4], r[5], r[6], r[7]);
      part[(kc * 3 + 2) * NROWS + row] = make_float4(r[8], r[9], r[10], r[11]);
    }
  }
}

// ---------------------------------------------------------------------------
// Kernel C: combine SPLIT partials and normalize. One thread per q-row.
// ---------------------------------------------------------------------------
__global__ __launch_bounds__(256) void combine_kernel(
    const float4* __restrict__ part, float* __restrict__ out) {
  int row = blockIdx.x * 256 + threadIdx.x;
  float r[12];
#pragma unroll
  for (int d = 0; d < 12; ++d) r[d] = 0.f;
#pragma unroll
  for (int kc = 0; kc < SPLIT; ++kc) {
#pragma unroll
    for (int c = 0; c < 3; ++c) {
      float4 t = part[(kc * 3 + c) * NROWS + row];
      r[4 * c + 0] += t.x;
      r[4 * c + 1] += t.y;
      r[4 * c + 2] += t.z;
      r[4 * c + 3] += t.w;
    }
  }
  float inv = 1.0f / r[11];
#pragma unroll
  for (int d = 0; d < OUTCH; ++d) out[(size_t)row * OUTCH + d] = r[d] * inv;
}

extern "C" void kernel_launch(void* const* d_in, const int* in_sizes, int n_in,
                              void* d_out, int out_size, void* d_ws, size_t ws_size,
                              hipStream_t stream) {
  const float* x = (const float*)d_in[0];
  const float* gamma = (const float*)d_in[1];
  const float* beta = (const float*)d_in[2];
  const float* W = (const float*)d_in[3];
  float4* ws = (float4*)d_ws;  // needs (9 + SPLIT*3)*NROWS*16 B ~= 1.9 MB
  float* out = (float*)d_out;

  qkv_ln_kernel<<<NROWS / 256, 256, 0, stream>>>(x, gamma, beta, W, ws);
  attn_kernel<<<(NROWS / 16) * SPLIT, 256, 0, stream>>>(ws, ws + PART_BASE);
  combine_kernel<<<NROWS / 256, 256, 0, stream>>>(ws + PART_BASE, out);
}

// Round 3
// 27.047 us; speedup vs baseline: 8.2432x; 8.2432x over previous
//
#include <hip/hip_runtime.h>

#define NROWS 8192
#define INCH 10
#define NQKV 33
#define OUTCH 11
#define SPLIT 16
#define KB 512            // k-rows per block (single LDS stage)
#define QBLK 128          // q-rows per block (4 waves x 32)

typedef short short8 __attribute__((ext_vector_type(8)));
typedef float f32x16 __attribute__((ext_vector_type(16)));
typedef unsigned int uvec4 __attribute__((ext_vector_type(4)));

// ws byte layout:
//   QB_OFF: Q bf16 [NROWS][16ch] rows of 32B (scale*log2e folded into q)
//   KB_OFF: K bf16 [NROWS][16ch]
//   VT_OFF: V^T bf16 interleaved: 16B unit u=(k>>3)*16+d holds V[k8*8+..][d],
//           d=0..10 v, d=11 ones (for softmax denom), d=12..15 zero
//   ACC_OFF: f32 [NROWS][12] atomic accumulators (o0..o10, l)
#define QB_OFF   0
#define KB_OFF   (NROWS * 32)
#define VT_OFF   (2 * NROWS * 32)
#define ACC_OFF  (3 * NROWS * 32)

__device__ inline unsigned short f2bf(float f) {
  unsigned u = __float_as_uint(f);
  unsigned r = (u + 0x7FFFu + ((u >> 16) & 1u)) >> 16;  // RNE
  return (unsigned short)r;
}

// ---------------------------------------------------------------------------
// Kernel A: LayerNorm + Linear(10->33); emit bf16 Q/K rows + interleaved V^T;
// zero the atomic accumulator (harness poisons ws once, we must re-zero every
// launch).
// ---------------------------------------------------------------------------
__global__ __launch_bounds__(256) void qkv_ln_kernel(
    const float* __restrict__ x, const float* __restrict__ gamma,
    const float* __restrict__ beta, const float* __restrict__ W,
    char* __restrict__ ws) {
  __shared__ float sW[NQKV * INCH];
  __shared__ float sg[INCH];
  __shared__ float sb[INCH];
  int tid = threadIdx.x;
  for (int i = tid; i < NQKV * INCH; i += 256) sW[i] = W[i];
  if (tid < INCH) { sg[tid] = gamma[tid]; sb[tid] = beta[tid]; }
  __syncthreads();

  int row = blockIdx.x * 256 + tid;
  float xv[INCH];
#pragma unroll
  for (int i = 0; i < INCH; ++i) xv[i] = x[row * INCH + i];

  float mu = 0.f;
#pragma unroll
  for (int i = 0; i < INCH; ++i) mu += xv[i];
  mu *= (1.0f / INCH);
  float var = 0.f;
#pragma unroll
  for (int i = 0; i < INCH; ++i) { float d = xv[i] - mu; var += d * d; }
  var *= (1.0f / INCH);
  float rstd = rsqrtf(var + 1e-5f);
  float h[INCH];
#pragma unroll
  for (int i = 0; i < INCH; ++i) h[i] = (xv[i] - mu) * rstd * sg[i] + sb[i];

  float acc[NQKV];
#pragma unroll
  for (int oc = 0; oc < NQKV; ++oc) {
    float s = 0.f;
#pragma unroll
    for (int i = 0; i < INCH; ++i) s += h[i] * sW[oc * INCH + i];
    acc[oc] = s;
  }

  // exp(s*scale) = exp2(s*scale*log2e): fold into q.
  const float QSC = 0.31622776601683794f * 1.4426950408889634f;

  unsigned short e[16];
  // ---- Q row ----
#pragma unroll
  for (int i = 0; i < 16; ++i) e[i] = (i < OUTCH) ? f2bf(acc[i] * QSC) : 0;
  unsigned qw[8];
#pragma unroll
  for (int i = 0; i < 8; ++i)
    qw[i] = (unsigned)e[2 * i] | ((unsigned)e[2 * i + 1] << 16);
  uint4* Qb = (uint4*)(ws + QB_OFF);
  Qb[row * 2 + 0] = make_uint4(qw[0], qw[1], qw[2], qw[3]);
  Qb[row * 2 + 1] = make_uint4(qw[4], qw[5], qw[6], qw[7]);
  // ---- K row ----
#pragma unroll
  for (int i = 0; i < 16; ++i) e[i] = (i < OUTCH) ? f2bf(acc[OUTCH + i]) : 0;
#pragma unroll
  for (int i = 0; i < 8; ++i)
    qw[i] = (unsigned)e[2 * i] | ((unsigned)e[2 * i + 1] << 16);
  uint4* Kb = (uint4*)(ws + KB_OFF);
  Kb[row * 2 + 0] = make_uint4(qw[0], qw[1], qw[2], qw[3]);
  Kb[row * 2 + 1] = make_uint4(qw[4], qw[5], qw[6], qw[7]);
  // ---- V^T scatter (2B stores into interleaved units) ----
  unsigned short* VTu = (unsigned short*)(ws + VT_OFF);
  int u0 = (row >> 3) * 16;
  int slot = row & 7;
#pragma unroll
  for (int d = 0; d < 16; ++d) {
    unsigned short v;
    if (d < OUTCH)      v = f2bf(acc[2 * OUTCH + d]);
    else if (d == OUTCH) v = 0x3F80;  // ones column -> softmax denominator
    else                 v = 0;
    VTu[(u0 + d) * 8 + slot] = v;
  }
  // ---- zero accumulators ----
  float4* A4 = (float4*)(ws + ACC_OFF);
  A4[row * 3 + 0] = make_float4(0.f, 0.f, 0.f, 0.f);
  A4[row * 3 + 1] = make_float4(0.f, 0.f, 0.f, 0.f);
  A4[row * 3 + 2] = make_float4(0.f, 0.f, 0.f, 0.f);
}

// ---------------------------------------------------------------------------
// Kernel B: MFMA flash attention partial. No row-max (|s|<=~13, fp32-safe,
// softmax shift-invariant). Per 32q x 32k tile:
//   S^T = mfma_32x32x16(A=K[32k x 16ch], B=Q[16ch x 32q]): lane owns q=lane&31,
//     16 k-values at k=(r&3)+8*(r>>2)+4h (h=lane>>5).
//   p = exp2(S); pack to bf16 pairs; cross-half swap builds PV A-frags.
//   O  = mfma_32x32x16(A=P[32q x 16k], B=V[16k x 32d]) x2 chunks, accumulated.
// V's ones-column makes O[.][11] = sum(p) = l. Epilogue: atomicAdd partials.
// ---------------------------------------------------------------------------
__global__ __launch_bounds__(256) void attn_kernel(const char* __restrict__ ws,
                                                   float* __restrict__ accum) {
  __shared__ uint4 sK[KB * 2];   // 16 KB: K rows, 32B each
  __shared__ uint4 sVT[KB * 2];  // 16 KB: V^T interleaved units

  const int tid = threadIdx.x;
  const int lane = tid & 63;
  const int wv = tid >> 6;
  const int h = lane >> 5;
  const int l31 = lane & 31;
  const int qc = blockIdx.x >> 4;  // SPLIT=16
  const int kc = blockIdx.x & 15;
  const int kt0 = kc * KB;
  const int q0 = qc * QBLK + wv * 32;

  const uint4* Qb = (const uint4*)(ws + QB_OFF);
  const uint4* Kb = (const uint4*)(ws + KB_OFF);
  const uint4* VTb = (const uint4*)(ws + VT_OFF);

  // stage K + V^T tile (linear copies; both layouts are linear in memory)
#pragma unroll
  for (int i = 0; i < 4; ++i) {
    sK[tid + 256 * i] = Kb[kt0 * 2 + tid + 256 * i];
    sVT[tid + 256 * i] = VTb[kt0 * 2 + tid + 256 * i];
  }

  // Q fragment: lane holds Q[q0 + (lane&31)][ch 8h..8h+7]
  short8 qf = *(const short8*)((const char*)Qb + (q0 + l31) * 32 + h * 16);

  f32x16 oacc;
#pragma unroll
  for (int r = 0; r < 16; ++r) oacc[r] = 0.f;
  f32x16 zf;
#pragma unroll
  for (int r = 0; r < 16; ++r) zf[r] = 0.f;

  __syncthreads();

  for (int it = 0; it < KB / 32; ++it) {
    // K fragment: lane holds K[it*32 + (lane&31)][ch 8h..8h+7]
    short8 kf = *(const short8*)((const char*)sK + it * 1024 + l31 * 32 + h * 16);
    // S^T[k][q] tile
    f32x16 s = __builtin_amdgcn_mfma_f32_32x32x16_bf16(kf, qf, zf, 0, 0, 0);

    float p[16];
#pragma unroll
    for (int r = 0; r < 16; ++r) p[r] = __builtin_amdgcn_exp2f(s[r]);

    // pack bf16 pairs (truncation; bias cancels in softmax ratio)
#define PK(a, b) __builtin_amdgcn_perm(__float_as_uint(b), __float_as_uint(a), 0x07060302u)
    unsigned P01 = PK(p[0], p[1]), P23 = PK(p[2], p[3]);
    unsigned P45 = PK(p[4], p[5]), P67 = PK(p[6], p[7]);
    unsigned P89 = PK(p[8], p[9]), Pab = PK(p[10], p[11]);
    unsigned Pcd = PK(p[12], p[13]), Pef = PK(p[14], p[15]);
#undef PK
    // cross-half partner values (lane ^ 32)
    unsigned X01 = (unsigned)__shfl_xor((int)P01, 32, 64);
    unsigned X23 = (unsigned)__shfl_xor((int)P23, 32, 64);
    unsigned X45 = (unsigned)__shfl_xor((int)P45, 32, 64);
    unsigned X67 = (unsigned)__shfl_xor((int)P67, 32, 64);
    unsigned X89 = (unsigned)__shfl_xor((int)P89, 32, 64);
    unsigned Xab = (unsigned)__shfl_xor((int)Pab, 32, 64);
    unsigned Xcd = (unsigned)__shfl_xor((int)Pcd, 32, 64);
    unsigned Xef = (unsigned)__shfl_xor((int)Pef, 32, 64);

    // PV A-frag chunk0 (k 0..15): word j = P[q][k=8h+2j..+2j+1]
    uvec4 c0 = {h ? X45 : P01, h ? X67 : P23, h ? P45 : X01, h ? P67 : X23};
    uvec4 c1 = {h ? Xcd : P89, h ? Xef : Pab, h ? Pcd : X89, h ? Pef : Xab};
    short8 a0 = __builtin_bit_cast(short8, c0);
    short8 a1 = __builtin_bit_cast(short8, c1);

    // V fragments: lane holds V[k=16c+8h+i][d=lane&15] (d>=16 lanes broadcast)
    const char* vb = (const char*)sVT;
    short8 v0 = *(const short8*)(vb + (it * 4 + h) * 256 + (lane & 15) * 16);
    short8 v1 = *(const short8*)(vb + (it * 4 + 2 + h) * 256 + (lane & 15) * 16);

    oacc = __builtin_amdgcn_mfma_f32_32x32x16_bf16(a0, v0, oacc, 0, 0, 0);
    oacc = __builtin_amdgcn_mfma_f32_32x32x16_bf16(a1, v1, oacc, 0, 0, 0);
  }

  // epilogue: O[q][d] partials; d = lane&31 (cols 12..31 unused)
  if (l31 < 12) {
#pragma unroll
    for (int r = 0; r < 16; ++r) {
      int q = (r & 3) + 8 * (r >> 2) + 4 * h;
      atomicAdd(&accum[(size_t)(q0 + q) * 12 + l31], oacc[r]);
    }
  }
}

// ---------------------------------------------------------------------------
// Kernel C: normalize. out[row][d] = o_d / l.
// ---------------------------------------------------------------------------
__global__ __launch_bounds__(256) void norm_kernel(const float* __restrict__ accum,
                                                   float* __restrict__ out) {
  int row = blockIdx.x * 256 + threadIdx.x;
  const float4* a4 = (const float4*)(accum + (size_t)row * 12);
  float4 a = a4[0], b = a4[1], c = a4[2];
  float inv = 1.0f / c.w;  // l
  float* o = out + (size_t)row * OUTCH;
  o[0] = a.x * inv; o[1] = a.y * inv; o[2] = a.z * inv; o[3] = a.w * inv;
  o[4] = b.x * inv; o[5] = b.y * inv; o[6] = b.z * inv; o[7] = b.w * inv;
  o[8] = c.x * inv; o[9] = c.y * inv; o[10] = c.z * inv;
}

extern "C" void kernel_launch(void* const* d_in, const int* in_sizes, int n_in,
                              void* d_out, int out_size, void* d_ws, size_t ws_size,
                              hipStream_t stream) {
  const float* x = (const float*)d_in[0];
  const float* gamma = (const float*)d_in[1];
  const float* beta = (const float*)d_in[2];
  const float* W = (const float*)d_in[3];
  char* ws = (char*)d_ws;  // needs 3*256KB + 384KB = 1.15 MB
  float* out = (float*)d_out;
  float* accum = (float*)(ws + ACC_OFF);

  qkv_ln_kernel<<<NROWS / 256, 256, 0, stream>>>(x, gamma, beta, W, ws);
  attn_kernel<<<(NROWS / QBLK) * SPLIT, 256, 0, stream>>>(ws, accum);
  norm_kernel<<<NROWS / 256, 256, 0, stream>>>(accum, out);
}

// Round 4
// 25.911 us; speedup vs baseline: 8.6047x; 1.0439x over previous
//
#include <hip/hip_runtime.h>

#define NROWS 8192
#define INCH 10
#define NQKV 33
#define OUTCH 11
#define SPLIT 16
#define KB 512            // k-rows per block (single LDS stage)
#define QBLK 128          // q-rows per block (4 waves x 32)

typedef short short8 __attribute__((ext_vector_type(8)));
typedef float f32x16 __attribute__((ext_vector_type(16)));
typedef unsigned int uvec4 __attribute__((ext_vector_type(4)));

// ws byte layout:
//   QB_OFF: Q bf16 [NROWS][16ch] rows of 32B (scale*log2e folded into q)
//   KB_OFF: K bf16 [NROWS][16ch]
//   VT_OFF: V^T bf16 interleaved: 16B unit u=(k>>3)*16+d holds V[k8*8+slot][d],
//           d=0..10 v, d=11 ones (softmax denom), d=12..15 zero
//   PART_OFF: f32 [SPLIT][NROWS][12] per-k-chunk partials (o0..o10, l)
#define QB_OFF   0
#define KB_OFF   (NROWS * 32)
#define VT_OFF   (2 * NROWS * 32)
#define PART_OFF (3 * NROWS * 32)

// v_permlane32_swap_b32 a, b:
//   a' = {a.lanes[0:31], b.lanes[0:31]}, b' = {a.lanes[32:63], b.lanes[32:63]}
#define SWAP32(a, b) asm("v_permlane32_swap_b32 %0, %1" : "+v"(a), "+v"(b))

__device__ inline unsigned short f2bf(float f) {
  unsigned u = __float_as_uint(f);
  unsigned r = (u + 0x7FFFu + ((u >> 16) & 1u)) >> 16;  // RNE
  return (unsigned short)r;
}

// ---------------------------------------------------------------------------
// Kernel A: LayerNorm + Linear(10->33); emit bf16 Q/K rows + interleaved V^T.
// ---------------------------------------------------------------------------
__global__ __launch_bounds__(128) void qkv_ln_kernel(
    const float* __restrict__ x, const float* __restrict__ gamma,
    const float* __restrict__ beta, const float* __restrict__ W,
    char* __restrict__ ws) {
  __shared__ float sW[NQKV * INCH];
  __shared__ float sg[INCH];
  __shared__ float sb[INCH];
  int tid = threadIdx.x;
  for (int i = tid; i < NQKV * INCH; i += 128) sW[i] = W[i];
  if (tid < INCH) { sg[tid] = gamma[tid]; sb[tid] = beta[tid]; }
  __syncthreads();

  int row = blockIdx.x * 128 + tid;
  const float2* x2 = (const float2*)x;  // rows are 40B = 5 float2, 8B aligned
  float xv[INCH];
#pragma unroll
  for (int j = 0; j < 5; ++j) {
    float2 t = x2[row * 5 + j];
    xv[2 * j] = t.x;
    xv[2 * j + 1] = t.y;
  }

  float mu = 0.f;
#pragma unroll
  for (int i = 0; i < INCH; ++i) mu += xv[i];
  mu *= (1.0f / INCH);
  float var = 0.f;
#pragma unroll
  for (int i = 0; i < INCH; ++i) { float d = xv[i] - mu; var += d * d; }
  var *= (1.0f / INCH);
  float rstd = rsqrtf(var + 1e-5f);
  float h[INCH];
#pragma unroll
  for (int i = 0; i < INCH; ++i) h[i] = (xv[i] - mu) * rstd * sg[i] + sb[i];

  float acc[NQKV];
#pragma unroll
  for (int oc = 0; oc < NQKV; ++oc) {
    float s = 0.f;
#pragma unroll
    for (int i = 0; i < INCH; ++i) s += h[i] * sW[oc * INCH + i];
    acc[oc] = s;
  }

  // exp(s*scale) = exp2(s*scale*log2e): fold into q.
  const float QSC = 0.31622776601683794f * 1.4426950408889634f;

  unsigned short e[16];
  unsigned qw[8];
  // ---- Q row ----
#pragma unroll
  for (int i = 0; i < 16; ++i) e[i] = (i < OUTCH) ? f2bf(acc[i] * QSC) : 0;
#pragma unroll
  for (int i = 0; i < 8; ++i)
    qw[i] = (unsigned)e[2 * i] | ((unsigned)e[2 * i + 1] << 16);
  uint4* Qb = (uint4*)(ws + QB_OFF);
  Qb[row * 2 + 0] = make_uint4(qw[0], qw[1], qw[2], qw[3]);
  Qb[row * 2 + 1] = make_uint4(qw[4], qw[5], qw[6], qw[7]);
  // ---- K row ----
#pragma unroll
  for (int i = 0; i < 16; ++i) e[i] = (i < OUTCH) ? f2bf(acc[OUTCH + i]) : 0;
#pragma unroll
  for (int i = 0; i < 8; ++i)
    qw[i] = (unsigned)e[2 * i] | ((unsigned)e[2 * i + 1] << 16);
  uint4* Kb = (uint4*)(ws + KB_OFF);
  Kb[row * 2 + 0] = make_uint4(qw[0], qw[1], qw[2], qw[3]);
  Kb[row * 2 + 1] = make_uint4(qw[4], qw[5], qw[6], qw[7]);
  // ---- V^T scatter (2B stores into interleaved units) ----
  unsigned short* VTu = (unsigned short*)(ws + VT_OFF);
  int u0 = (row >> 3) * 16;
  int slot = row & 7;
#pragma unroll
  for (int d = 0; d < 16; ++d) {
    unsigned short v;
    if (d < OUTCH)       v = f2bf(acc[2 * OUTCH + d]);
    else if (d == OUTCH) v = 0x3F80;  // ones column -> softmax denominator
    else                 v = 0;
    VTu[(u0 + d) * 8 + slot] = v;
  }
}

// ---------------------------------------------------------------------------
// Kernel B: MFMA flash attention partial. No row-max (|s|<=~13, fp32-safe,
// softmax shift-invariant). Per 32q x 32k tile:
//   S^T = mfma_32x32x16(A=K, B=Q): lane owns q=lane&31, 16 k at
//         k=(r&3)+8*(r>>2)+4h, h=lane>>5.
//   p = exp2(S); v_perm pack to bf16 pairs; v_permlane32_swap builds PV
//   A-frags (replaces 8 ds_bpermute + 16 cndmask).
//   O += mfma_32x32x16(A=P, B=V) x2. V ones-column gives l for free.
// Per-(qc,kc) partials stored plain (no atomics).
// ---------------------------------------------------------------------------
__global__ __launch_bounds__(256) void attn_kernel(const char* __restrict__ ws,
                                                   float* __restrict__ part) {
  __shared__ uint4 sK[KB * 2];   // 16 KB: K rows, 32B each
  __shared__ uint4 sVT[KB * 2];  // 16 KB: V^T interleaved units

  const int tid = threadIdx.x;
  const int lane = tid & 63;
  const int wv = tid >> 6;
  const int h = lane >> 5;
  const int l31 = lane & 31;
  const int qc = blockIdx.x >> 4;  // SPLIT=16
  const int kc = blockIdx.x & 15;
  const int kt0 = kc * KB;
  const int q0 = qc * QBLK + wv * 32;

  const uint4* Qb = (const uint4*)(ws + QB_OFF);
  const uint4* gK = (const uint4*)(ws + KB_OFF) + kt0 * 2;
  const uint4* gV = (const uint4*)(ws + VT_OFF) + kt0 * 2;

  // async global->LDS staging, 16B/lane, wave-linear dest
#pragma unroll
  for (int i = 0; i < 4; ++i) {
    int o = wv * 64 + 256 * i;
    __builtin_amdgcn_global_load_lds(
        (const __attribute__((address_space(1))) void*)(gK + o + lane),
        (__attribute__((address_space(3))) void*)(sK + o), 16, 0, 0);
    __builtin_amdgcn_global_load_lds(
        (const __attribute__((address_space(1))) void*)(gV + o + lane),
        (__attribute__((address_space(3))) void*)(sVT + o), 16, 0, 0);
  }

  // Q fragment: lane holds Q[q0 + (lane&31)][ch 8h..8h+7]
  short8 qf = *(const short8*)((const char*)Qb + (q0 + l31) * 32 + h * 16);

  f32x16 oacc;
#pragma unroll
  for (int r = 0; r < 16; ++r) oacc[r] = 0.f;
  f32x16 zf;
#pragma unroll
  for (int r = 0; r < 16; ++r) zf[r] = 0.f;

  __syncthreads();

  for (int it = 0; it < KB / 32; ++it) {
    // K fragment: lane holds K[it*32 + (lane&31)][ch 8h..8h+7]
    short8 kf = *(const short8*)((const char*)sK + it * 1024 + l31 * 32 + h * 16);
    // S^T[k][q] tile
    f32x16 s = __builtin_amdgcn_mfma_f32_32x32x16_bf16(kf, qf, zf, 0, 0, 0);

    float p[16];
#pragma unroll
    for (int r = 0; r < 16; ++r) p[r] = __builtin_amdgcn_exp2f(s[r]);

    // pack bf16 pairs (truncation; bias cancels in softmax ratio)
#define PK(a, b) __builtin_amdgcn_perm(__float_as_uint(b), __float_as_uint(a), 0x07060302u)
    unsigned P01 = PK(p[0], p[1]), P23 = PK(p[2], p[3]);
    unsigned P45 = PK(p[4], p[5]), P67 = PK(p[6], p[7]);
    unsigned P89 = PK(p[8], p[9]), Pab = PK(p[10], p[11]);
    unsigned Pcd = PK(p[12], p[13]), Pef = PK(p[14], p[15]);
#undef PK
    // cross-half exchange: one swap fills two PV A-frag words
    SWAP32(P01, P45);
    SWAP32(P23, P67);
    SWAP32(P89, Pcd);
    SWAP32(Pab, Pef);

    uvec4 c0 = {P01, P23, P45, P67};  // k 0..15: word j = P[q][k=8h+2j..+2j+1]
    uvec4 c1 = {P89, Pab, Pcd, Pef};  // k 16..31
    short8 a0 = __builtin_bit_cast(short8, c0);
    short8 a1 = __builtin_bit_cast(short8, c1);

    // V fragments: lane holds V[k=16c+8h+i][d=lane&15]
    const char* vb = (const char*)sVT;
    short8 v0 = *(const short8*)(vb + (it * 4 + h) * 256 + (lane & 15) * 16);
    short8 v1 = *(const short8*)(vb + (it * 4 + 2 + h) * 256 + (lane & 15) * 16);

    oacc = __builtin_amdgcn_mfma_f32_32x32x16_bf16(a0, v0, oacc, 0, 0, 0);
    oacc = __builtin_amdgcn_mfma_f32_32x32x16_bf16(a1, v1, oacc, 0, 0, 0);
  }

  // epilogue: per-(q,d) partial store; d = lane&31 < 12, q unique per (r,h)
  if (l31 < 12) {
#pragma unroll
    for (int r = 0; r < 16; ++r) {
      int q = (r & 3) + 8 * (r >> 2) + 4 * h;
      part[((size_t)kc * NROWS + q0 + q) * 12 + l31] = oacc[r];
    }
  }
}

// ---------------------------------------------------------------------------
// Kernel C: combine SPLIT partials and normalize.
// ---------------------------------------------------------------------------
__global__ __launch_bounds__(128) void norm_kernel(const float* __restrict__ part,
                                                   float* __restrict__ out) {
  int row = blockIdx.x * 128 + threadIdx.x;
  const float4* p4 = (const float4*)part;
  float r[12];
#pragma unroll
  for (int d = 0; d < 12; ++d) r[d] = 0.f;
#pragma unroll
  for (int kc = 0; kc < SPLIT; ++kc) {
    size_t b = ((size_t)kc * NROWS + row) * 3;
    float4 t0 = p4[b], t1 = p4[b + 1], t2 = p4[b + 2];
    r[0] += t0.x; r[1] += t0.y; r[2] += t0.z; r[3] += t0.w;
    r[4] += t1.x; r[5] += t1.y; r[6] += t1.z; r[7] += t1.w;
    r[8] += t2.x; r[9] += t2.y; r[10] += t2.z; r[11] += t2.w;
  }
  float inv = 1.0f / r[11];
  float* o = out + (size_t)row * OUTCH;
#pragma unroll
  for (int d = 0; d < OUTCH; ++d) o[d] = r[d] * inv;
}

extern "C" void kernel_launch(void* const* d_in, const int* in_sizes, int n_in,
                              void* d_out, int out_size, void* d_ws, size_t ws_size,
                              hipStream_t stream) {
  const float* x = (const float*)d_in[0];
  const float* gamma = (const float*)d_in[1];
  const float* beta = (const float*)d_in[2];
  const float* W = (const float*)d_in[3];
  char* ws = (char*)d_ws;  // needs 768 KB + 6.3 MB partials ~= 7.1 MB
  float* out = (float*)d_out;
  float* part = (float*)(ws + PART_OFF);

  qkv_ln_kernel<<<NROWS / 128, 128, 0, stream>>>(x, gamma, beta, W, ws);
  attn_kernel<<<(NROWS / QBLK) * SPLIT, 256, 0, stream>>>(ws, part);
  norm_kernel<<<NROWS / 128, 128, 0, stream>>>(part, out);
}